// Round 1
// baseline (1937.565 us; speedup 1.0000x reference)
//
#include <hip/hip_runtime.h>
#include <math.h>

// Gated DeltaNet chunkwise recurrence, MI355X (gfx950).
// Decomposition: grid = 32 (B*H) x 8 (Dv/32) independent workgroups.
// Each workgroup owns S[:, vslice] (128x32 fp32 in LDS) and walks the 64
// chunks sequentially. v-independent quantities (q/k norms, gates, A, Aqk,
// triangular solve T) are recomputed redundantly per v-slice (8x) — no
// workspace, no inter-WG sync. correction = T @ (v_g - k_g @ S) removes W.

namespace {

constexpr int kBH      = 32;     // B*H
constexpr int kS       = 4096;
constexpr int kDk      = 128;
constexpr int kDv      = 256;
constexpr int kL       = 64;     // chunk length
constexpr int kNC      = kS / kL;
constexpr int kVb      = 32;     // v-slice width per workgroup
constexpr int kThreads = 512;
constexpr float kScale = 0.08838834764831845f;  // 128^-0.5
constexpr float kEps   = 1e-6f;

// LDS row strides (floats), padded for bank behavior + 16B float4 alignment
constexpr int KST = 72;   // sKnT/sQnT: [128][72]
constexpr int SST = 36;   // sS/sY:     [128][36] / [64][36]
constexpr int AST = 68;   // sAT/sAqk:  [64][68]

__global__ __launch_bounds__(kThreads, 2)
void gdn_chunk_kernel(const float* __restrict__ q, const float* __restrict__ k,
                      const float* __restrict__ v, const float* __restrict__ g,
                      const float* __restrict__ beta, float* __restrict__ out) {
  __shared__ float sKnT[kDk][KST];   // normalized k, transposed: sKnT[d][i]
  __shared__ float sQnT[kDk][KST];   // normalized q, transposed
  __shared__ float sS[kDk][SST];     // state slice S[d][v]
  __shared__ float sAT[kL][AST];     // A, then (in-place) T
  __shared__ float sAqk[kL][AST];    // scaled/gated q.k^T (causal)
  __shared__ float sY[kL][SST];      // Y = v_g - k_g S, then correction
  __shared__ float sVinv[4][16][17]; // inverses of 16x16 diagonal blocks
  __shared__ float sTmp[3][16][17];  // block-solve temp
  __shared__ float sGcum[kL];
  __shared__ float sGexp[kL];
  __shared__ float sBeta[kL];

  const int t  = threadIdx.x;
  const int bh = blockIdx.x & 31;   // same-head vslices land on same XCD
  const int vb = blockIdx.x >> 5;

  const float* qp = q    + (size_t)bh * kS * kDk;
  const float* kp = k    + (size_t)bh * kS * kDk;
  const float* vp = v    + (size_t)bh * kS * kDv + vb * kVb;
  const float* gp = g    + (size_t)bh * kS;
  const float* bp = beta + (size_t)bh * kS;
  float* op = out + (size_t)bh * kS * kDv + vb * kVb;
  float* sp = out + (size_t)kBH * kS * kDv + (size_t)bh * kDk * kDv + vb * kVb;

  const int r2 = t >> 3;  // 0..63: row i (steps 3,5-7), d (step 8), load row
  const int c8 = t & 7;   // 0..7 : col-16 group (load), j-octet (step 3), v-quad

  // S0 = 0
  for (int idx = t; idx < kDk * SST; idx += kThreads) (&sS[0][0])[idx] = 0.f;

  float oint[4];  // O_inter per-thread accumulators (steps 5 -> 7)

  for (int n = 0; n < kNC; ++n) {
    __syncthreads();  // protects sKnT/sQnT/gates/sS vs previous chunk's users

    // ---- gates: cumsum of g over the chunk (wave 0) ----
    if (t < kL) {
      float gv = gp[n * kL + t];
      sBeta[t] = bp[n * kL + t];
      #pragma unroll
      for (int off = 1; off < 64; off <<= 1) {
        float up = __shfl_up(gv, off, 64);
        if (t >= off) gv += up;
      }
      sGcum[t] = gv;
      sGexp[t] = __expf(gv);
    }

    // ---- load + L2-normalize q,k rows; write transposed to LDS ----
    {
      const float* krow = kp + (size_t)(n * kL + r2) * kDk + c8 * 16;
      const float* qrow = qp + (size_t)(n * kL + r2) * kDk + c8 * 16;
      float kv[16], qv[16];
      float ssk = 0.f, ssq = 0.f;
      #pragma unroll
      for (int m = 0; m < 4; ++m) {
        const float4 a = reinterpret_cast<const float4*>(krow)[m];
        const float4 b = reinterpret_cast<const float4*>(qrow)[m];
        kv[4*m+0]=a.x; kv[4*m+1]=a.y; kv[4*m+2]=a.z; kv[4*m+3]=a.w;
        qv[4*m+0]=b.x; qv[4*m+1]=b.y; qv[4*m+2]=b.z; qv[4*m+3]=b.w;
        ssk += a.x*a.x + a.y*a.y + a.z*a.z + a.w*a.w;
        ssq += b.x*b.x + b.y*b.y + b.z*b.z + b.w*b.w;
      }
      #pragma unroll
      for (int off = 4; off >= 1; off >>= 1) {
        ssk += __shfl_xor(ssk, off, 8);
        ssq += __shfl_xor(ssq, off, 8);
      }
      const float rk = 1.f / (sqrtf(ssk) + kEps);
      const float rq = 1.f / (sqrtf(ssq) + kEps);
      #pragma unroll
      for (int m = 0; m < 16; ++m) {
        sKnT[c8 * 16 + m][r2] = kv[m] * rk;
        sQnT[c8 * 16 + m][r2] = qv[m] * rq;
      }
    }
    __syncthreads();

    // ---- A (I + beta_i * k_i.k_j * relgate, strictly lower) and Aqk ----
    // thread: i = r2, j = 8*c8 + m  (16 dots of K=128 per thread)
    {
      const int i = r2;
      float kkv[8] = {0,0,0,0,0,0,0,0};
      float qkv[8] = {0,0,0,0,0,0,0,0};
      #pragma unroll 2
      for (int d = 0; d < kDk; ++d) {
        const float4 ka  = *reinterpret_cast<const float4*>(&sKnT[d][8*c8]);
        const float4 kb4 = *reinterpret_cast<const float4*>(&sKnT[d][8*c8+4]);
        const float kb = sKnT[d][i];
        const float qb = sQnT[d][i];
        const float kj[8] = {ka.x,ka.y,ka.z,ka.w,kb4.x,kb4.y,kb4.z,kb4.w};
        #pragma unroll
        for (int m = 0; m < 8; ++m) {
          kkv[m] += kb * kj[m];
          qkv[m] += qb * kj[m];
        }
      }
      const float gi = sGcum[i];
      const float bi = sBeta[i];
      float ao[8], qo[8];
      #pragma unroll
      for (int m = 0; m < 8; ++m) {
        const int j = 8*c8 + m;
        const float rel = __expf(sGcum[j] - gi);  // relgate[i][j]
        ao[m] = (j < i)  ? bi * kkv[m] * rel : ((j == i) ? 1.f : 0.f);
        qo[m] = (j <= i) ? kScale * qkv[m] * rel : 0.f;
      }
      *reinterpret_cast<float4*>(&sAT[i][8*c8])    = make_float4(ao[0],ao[1],ao[2],ao[3]);
      *reinterpret_cast<float4*>(&sAT[i][8*c8+4])  = make_float4(ao[4],ao[5],ao[6],ao[7]);
      *reinterpret_cast<float4*>(&sAqk[i][8*c8])   = make_float4(qo[0],qo[1],qo[2],qo[3]);
      *reinterpret_cast<float4*>(&sAqk[i][8*c8+4]) = make_float4(qo[4],qo[5],qo[6],qo[7]);
    }
    __syncthreads();

    // ---- blocked triangular solve: T = A^{-1} diag(beta), in place in sAT ----
    // 4a: invert the four 16x16 unit-lower diagonal blocks (forward subst.)
    if (t < 64) {
      const int I = t >> 4, c = t & 15;
      float x[16];
      #pragma unroll
      for (int i = 0; i < 16; ++i) {
        float xi = (i == c) ? 1.f : 0.f;
        #pragma unroll
        for (int j = 0; j < 16; ++j) {
          if (j < i) xi -= sAT[I*16 + i][I*16 + j] * x[j];
        }
        x[i] = xi;
      }
      #pragma unroll
      for (int i = 0; i < 16; ++i) sVinv[I][i][c] = x[i];
    }
    __syncthreads();
    // 4b: block-row forward substitution (rows of T replace rows of A)
    for (int I = 0; I < 4; ++I) {
      if (I > 0) {
        for (int J = t >> 8; J < I; J += 2) {
          const int r = (t >> 4) & 15, c = t & 15;
          float s = 0.f;
          for (int K = J; K < I; ++K) {
            #pragma unroll
            for (int ss = 0; ss < 16; ++ss)
              s += sAT[I*16 + r][K*16 + ss] * sAT[K*16 + ss][J*16 + c];
          }
          sTmp[J][r][c] = s;
        }
        __syncthreads();
      }
      for (int J = t >> 8; J <= I; J += 2) {
        const int r = (t >> 4) & 15, c = t & 15;
        if (J == I) {
          sAT[I*16 + r][I*16 + c] = sVinv[I][r][c] * sBeta[I*16 + c];
        } else {
          float s = 0.f;
          #pragma unroll
          for (int ss = 0; ss < 16; ++ss) s += sVinv[I][r][ss] * sTmp[J][ss][c];
          sAT[I*16 + r][J*16 + c] = -s;
        }
      }
      __syncthreads();
    }

    // ---- Y = gexp_i * (v_i - k_i . S)   and O_inter = gexp_i*SCALE * q_i.S ----
    {
      const int i = r2, v4 = c8;
      float ky[4] = {0,0,0,0}, qs[4] = {0,0,0,0};
      #pragma unroll 2
      for (int d = 0; d < kDk; ++d) {
        const float4 sv = *reinterpret_cast<const float4*>(&sS[d][4*v4]);
        const float kb = sKnT[d][i];
        const float qb = sQnT[d][i];
        ky[0] += kb*sv.x; ky[1] += kb*sv.y; ky[2] += kb*sv.z; ky[3] += kb*sv.w;
        qs[0] += qb*sv.x; qs[1] += qb*sv.y; qs[2] += qb*sv.z; qs[3] += qb*sv.w;
      }
      const float4 vv = *reinterpret_cast<const float4*>(
          vp + (size_t)(n * kL + i) * kDv + 4*v4);
      const float ge = sGexp[i];
      sY[i][4*v4+0] = ge * (vv.x - ky[0]);
      sY[i][4*v4+1] = ge * (vv.y - ky[1]);
      sY[i][4*v4+2] = ge * (vv.z - ky[2]);
      sY[i][4*v4+3] = ge * (vv.w - ky[3]);
      const float os = ge * kScale;
      oint[0] = qs[0]*os; oint[1] = qs[1]*os; oint[2] = qs[2]*os; oint[3] = qs[3]*os;
    }
    __syncthreads();

    // ---- correction = T @ Y (into registers, then overwrite sY) ----
    float cor[4] = {0,0,0,0};
    {
      const int i = r2, v4 = c8;
      #pragma unroll 2
      for (int j = 0; j < kL; ++j) {
        const float4 yv = *reinterpret_cast<const float4*>(&sY[j][4*v4]);
        const float tb = sAT[i][j];
        cor[0] += tb*yv.x; cor[1] += tb*yv.y; cor[2] += tb*yv.z; cor[3] += tb*yv.w;
      }
    }
    __syncthreads();
    sY[r2][4*c8+0] = cor[0];
    sY[r2][4*c8+1] = cor[1];
    sY[r2][4*c8+2] = cor[2];
    sY[r2][4*c8+3] = cor[3];
    __syncthreads();

    // ---- O = O_inter + Aqk @ correction  -> global ----
    {
      const int i = r2, v4 = c8;
      float o0 = oint[0], o1 = oint[1], o2 = oint[2], o3 = oint[3];
      #pragma unroll 2
      for (int j = 0; j < kL; ++j) {
        const float4 cv = *reinterpret_cast<const float4*>(&sY[j][4*v4]);
        const float ab = sAqk[i][j];
        o0 += ab*cv.x; o1 += ab*cv.y; o2 += ab*cv.z; o3 += ab*cv.w;
      }
      *reinterpret_cast<float4*>(op + (size_t)(n * kL + r2) * kDv + 4*c8) =
          make_float4(o0, o1, o2, o3);
    }

    // ---- S = decay*S + k_g^T @ correction (two d-rows per thread) ----
    {
      const float decay = sGexp[kL - 1];
      const int d0 = r2, d1 = r2 + 64, v4 = c8;
      float a0[4] = {0,0,0,0}, a1[4] = {0,0,0,0};
      #pragma unroll 2
      for (int i = 0; i < kL; ++i) {
        const float4 cv = *reinterpret_cast<const float4*>(&sY[i][4*v4]);
        const float ge = sGexp[i];
        const float kb0 = sKnT[d0][i] * ge;
        const float kb1 = sKnT[d1][i] * ge;
        a0[0] += kb0*cv.x; a0[1] += kb0*cv.y; a0[2] += kb0*cv.z; a0[3] += kb0*cv.w;
        a1[0] += kb1*cv.x; a1[1] += kb1*cv.y; a1[2] += kb1*cv.z; a1[3] += kb1*cv.w;
      }
      float4 s0 = *reinterpret_cast<float4*>(&sS[d0][4*v4]);
      s0.x = decay*s0.x + a0[0]; s0.y = decay*s0.y + a0[1];
      s0.z = decay*s0.z + a0[2]; s0.w = decay*s0.w + a0[3];
      *reinterpret_cast<float4*>(&sS[d0][4*v4]) = s0;
      float4 s1 = *reinterpret_cast<float4*>(&sS[d1][4*v4]);
      s1.x = decay*s1.x + a1[0]; s1.y = decay*s1.y + a1[1];
      s1.z = decay*s1.z + a1[2]; s1.w = decay*s1.w + a1[3];
      *reinterpret_cast<float4*>(&sS[d1][4*v4]) = s1;
    }
  }

  // ---- final state -> d_out tail (each thread wrote its own S quads) ----
  __syncthreads();
  #pragma unroll
  for (int p = 0; p < 2; ++p) {
    const int d = r2 + 64 * p;
    const float4 sv = *reinterpret_cast<const float4*>(&sS[d][4*c8]);
    *reinterpret_cast<float4*>(sp + (size_t)d * kDv + 4*c8) = sv;
  }
}

}  // namespace

extern "C" void kernel_launch(void* const* d_in, const int* in_sizes, int n_in,
                              void* d_out, int out_size, void* d_ws, size_t ws_size,
                              hipStream_t stream) {
  (void)in_sizes; (void)n_in; (void)d_ws; (void)ws_size; (void)out_size;
  const float* q    = (const float*)d_in[0];
  const float* k    = (const float*)d_in[1];
  const float* v    = (const float*)d_in[2];
  const float* g    = (const float*)d_in[3];
  const float* beta = (const float*)d_in[4];
  float* out = (float*)d_out;
  gdn_chunk_kernel<<<dim3(kBH * (kDv / kVb)), dim3(kThreads), 0, stream>>>(
      q, k, v, g, beta, out);
}

// Round 2
// 959.920 us; speedup vs baseline: 2.0185x; 2.0185x over previous
//
#include <hip/hip_runtime.h>
#include <math.h>

// Gated DeltaNet chunkwise recurrence on MFMA (gfx950).
// grid = 32 heads x 8 v-slices (32 cols each); 512 thr = 8 waves per WG.
// Gates folded into operands: kp=k*e^{gc}, km=k*e^{-gc}, qp=scale*q*e^{gc},
// qm=scale*q*e^{-gc}  =>  KK*relgate = km.kp^T, Aqk = qm.kp^T (masked),
// Y = gexp*V - kp.S, O = qp.S + Aqk.cor, S' = decay*S + kp^T.cor.
// S state lives in MFMA accumulators of waves 0-3 (C-init = decay*S).
// 64x64 unit-lower solve: fp32 block inverse (16-diag -> 16-offdiag -> 32x32),
// interleaved with the [kp;qp].S MFMA phase running on waves 4-7.

namespace {

constexpr int kBH = 32;
constexpr int kS = 4096;
constexpr int kDk = 128;
constexpr int kDv = 256;
constexpr int kL = 64;
constexpr int kNC = kS / kL;
constexpr int kThreads = 512;
constexpr float kScale = 0.08838834764831845f;  // 128^-0.5
constexpr float kEps = 1e-6f;

constexpr int KST = 136;  // bf16 row stride, 128-col mats (68 words = even banks)
constexpr int TST = 72;   // bf16 row stride, 64-col mats (36 words)
constexpr int SBT = 136;  // bf16 row stride for S^T snapshot
constexpr int AS  = 68;   // fp32 row stride for A / solve

typedef __attribute__((ext_vector_type(8))) short short8;
typedef __attribute__((ext_vector_type(4))) short short4v;
typedef __attribute__((ext_vector_type(4))) float f32x4;

__device__ __forceinline__ short f2bf(float f) {
  union { float f; unsigned u; } x;
  x.f = f;
  unsigned r = x.u + 0x7fffu + ((x.u >> 16) & 1u);  // RNE
  return (short)(r >> 16);
}

#define MFMA16(a, b, c) __builtin_amdgcn_mfma_f32_16x16x32_bf16((a), (b), (c), 0, 0, 0)

__global__ __launch_bounds__(kThreads, 2)
void gdn_mfma_kernel(const float* __restrict__ q, const float* __restrict__ k,
                     const float* __restrict__ v, const float* __restrict__ g,
                     const float* __restrict__ beta, float* __restrict__ out) {
  __shared__ short sKp[kL][KST];   // k * e^{gc}        (rows i, cols d)
  __shared__ short sKm[kL][KST];   // k * e^{-gc}
  __shared__ short sQp[kL][KST];   // scale * q * e^{gc}
  __shared__ short sQm[kL][KST];   // scale * q * e^{-gc}
  __shared__ short sTb[kL][TST];   // T, bf16 (upper stays 0 forever)
  __shared__ short sAqk[kL][TST];  // masked gated qk^T (upper stays 0)
  __shared__ short sSb[32][SBT];   // S^T snapshot bf16: [v][d]
  __shared__ short sYT[32][TST];   // Y^T bf16: [v][i]
  __shared__ short sCT[32][TST];   // cor^T bf16: [v][i]
  __shared__ float sA[kL][AS];     // strictly-lower A (fp32), solve scratch
  __shared__ float sVinv[4][16][17];
  __shared__ float sTmp[32][33];
  __shared__ float sGexp[kL], sGinv[kL], sBeta[kL];

  const int t = threadIdx.x;
  const int wave = t >> 6;
  const int lane = t & 63;
  const int n16 = lane & 15;
  const int quad = lane >> 4;
  const int r2 = t >> 3;  // 0..63 staging row
  const int c8 = t & 7;   // 16-col group within row

  const int bh = blockIdx.x & 31;
  const int vb = blockIdx.x >> 5;

  const float* qp_g = q + (size_t)bh * kS * kDk;
  const float* kp_g = k + (size_t)bh * kS * kDk;
  const float* vp_g = v + (size_t)bh * kS * kDv + vb * 32;
  const float* gp_g = g + (size_t)bh * kS;
  const float* bp_g = beta + (size_t)bh * kS;
  float* op_g = out + (size_t)bh * kS * kDv + vb * 32;
  float* sp_g = out + (size_t)kBH * kS * kDv + (size_t)bh * kDk * kDv + vb * 32;

  // persistent-zero regions (upper triangles never rewritten) + S^T snapshot
  for (int i = t; i < kL * TST; i += kThreads) { (&sTb[0][0])[i] = 0; (&sAqk[0][0])[i] = 0; }
  for (int i = t; i < 32 * SBT; i += kThreads) (&sSb[0][0])[i] = 0;

  f32x4 Sacc[4];  // waves 0-3: state tiles (d0=32w+16a, v0=16b) -> Sacc[2a+b]
  Sacc[0] = 0; Sacc[1] = 0; Sacc[2] = 0; Sacc[3] = 0;

  for (int n = 0; n < kNC; ++n) {
    __syncthreads();  // b0: previous chunk fully consumed

    // ---- stage1: global loads + norms (regs); wave0: gates ----
    float kv[16], qv[16], rk, rq;
    {
      const float* krow = kp_g + (size_t)(n * kL + r2) * kDk + c8 * 16;
      const float* qrow = qp_g + (size_t)(n * kL + r2) * kDk + c8 * 16;
      float ssk = 0.f, ssq = 0.f;
      #pragma unroll
      for (int m = 0; m < 4; ++m) {
        const float4 a = reinterpret_cast<const float4*>(krow)[m];
        const float4 b = reinterpret_cast<const float4*>(qrow)[m];
        kv[4*m+0]=a.x; kv[4*m+1]=a.y; kv[4*m+2]=a.z; kv[4*m+3]=a.w;
        qv[4*m+0]=b.x; qv[4*m+1]=b.y; qv[4*m+2]=b.z; qv[4*m+3]=b.w;
        ssk += a.x*a.x + a.y*a.y + a.z*a.z + a.w*a.w;
        ssq += b.x*b.x + b.y*b.y + b.z*b.z + b.w*b.w;
      }
      #pragma unroll
      for (int off = 4; off >= 1; off >>= 1) {
        ssk += __shfl_xor(ssk, off, 8);
        ssq += __shfl_xor(ssq, off, 8);
      }
      rk = 1.f / (sqrtf(ssk) + kEps);
      rq = 1.f / (sqrtf(ssq) + kEps);
    }
    if (t < kL) {
      float gv = gp_g[n * kL + t];
      float bt = bp_g[n * kL + t];
      #pragma unroll
      for (int off = 1; off < 64; off <<= 1) {
        float up = __shfl_up(gv, off, 64);
        if (lane >= off) gv += up;
      }
      sGexp[t] = __expf(gv);
      sGinv[t] = __expf(-gv);
      sBeta[t] = bt;
    }
    __syncthreads();  // b1: gates visible

    // ---- stage2: write the four gated bf16 operand matrices ----
    {
      const float ge = sGexp[r2], gi = sGinv[r2];
      const float m_kp = rk * ge, m_km = rk * gi;
      const float m_qp = rq * ge * kScale, m_qm = rq * gi * kScale;
      short8 w0, w1;
      #pragma unroll
      for (int m = 0; m < 8; ++m) { w0[m] = f2bf(kv[m] * m_kp); w1[m] = f2bf(kv[8+m] * m_kp); }
      *(short8*)&sKp[r2][c8*16] = w0; *(short8*)&sKp[r2][c8*16+8] = w1;
      #pragma unroll
      for (int m = 0; m < 8; ++m) { w0[m] = f2bf(kv[m] * m_km); w1[m] = f2bf(kv[8+m] * m_km); }
      *(short8*)&sKm[r2][c8*16] = w0; *(short8*)&sKm[r2][c8*16+8] = w1;
      #pragma unroll
      for (int m = 0; m < 8; ++m) { w0[m] = f2bf(qv[m] * m_qp); w1[m] = f2bf(qv[8+m] * m_qp); }
      *(short8*)&sQp[r2][c8*16] = w0; *(short8*)&sQp[r2][c8*16+8] = w1;
      #pragma unroll
      for (int m = 0; m < 8; ++m) { w0[m] = f2bf(qv[m] * m_qm); w1[m] = f2bf(qv[8+m] * m_qm); }
      *(short8*)&sQm[r2][c8*16] = w0; *(short8*)&sQm[r2][c8*16+8] = w1;
    }
    __syncthreads();  // b2: operands visible

    // ---- PA: KK (waves 0-3 -> strictly-lower A) / QK (waves 4-7 -> Aqk) ----
    {
      const int jmax = wave & 3;
      const int i0 = (wave & 3) * 16;
      const short (*Asrc)[KST] = (wave < 4) ? sKm : sQm;
      f32x4 acc[4];
      acc[0] = 0; acc[1] = 0; acc[2] = 0; acc[3] = 0;
      #pragma unroll
      for (int ks = 0; ks < 4; ++ks) {
        short8 af = *(const short8*)&Asrc[i0 + n16][ks*32 + quad*8];
        for (int jt = 0; jt <= jmax; ++jt) {
          short8 bf = *(const short8*)&sKp[jt*16 + n16][ks*32 + quad*8];
          acc[jt] = MFMA16(af, bf, acc[jt]);
        }
      }
      if (wave < 4) {
        #pragma unroll
        for (int reg = 0; reg < 4; ++reg) {
          const int i = i0 + quad*4 + reg;
          const float bi = sBeta[i];
          for (int jt = 0; jt <= jmax; ++jt) {
            const int j = jt*16 + n16;
            if (j < i) sA[i][j] = bi * acc[jt][reg];
          }
        }
      } else {
        for (int jt = 0; jt <= jmax; ++jt) {
          #pragma unroll
          for (int reg = 0; reg < 4; ++reg) {
            const int i = i0 + quad*4 + reg, j = jt*16 + n16;
            sAqk[i][j] = (j <= i) ? f2bf(acc[jt][reg]) : (short)0;
          }
        }
      }
    }
    __syncthreads();  // b3

    // ---- interleaved: solve (waves 0-3, fp32) || PY = [kp;qp].S (waves 4-7) ----
    f32x4 yacc[2], oacc[2];
    float vv[2][4];
    const int iy0 = (wave & 3) * 16;
    auto py_step = [&](int ks) {
      short8 ak = *(const short8*)&sKp[iy0 + n16][ks*32 + quad*8];
      short8 aq = *(const short8*)&sQp[iy0 + n16][ks*32 + quad*8];
      #pragma unroll
      for (int vt = 0; vt < 2; ++vt) {
        short8 bs = *(const short8*)&sSb[vt*16 + n16][ks*32 + quad*8];
        yacc[vt] = MFMA16(ak, bs, yacc[vt]);
        oacc[vt] = MFMA16(aq, bs, oacc[vt]);
      }
    };

    if (wave >= 4) {
      yacc[0] = 0; yacc[1] = 0; oacc[0] = 0; oacc[1] = 0;
      #pragma unroll
      for (int vt = 0; vt < 2; ++vt)
        #pragma unroll
        for (int reg = 0; reg < 4; ++reg)
          vv[vt][reg] = vp_g[(size_t)(n*kL + iy0 + quad*4 + reg) * kDv + vt*16 + n16];
      py_step(0);
    } else if (t < 64) {
      // S1: invert the four 16x16 unit-lower diagonal blocks
      const int I = t >> 4, c = t & 15;
      float x[16];
      #pragma unroll
      for (int i = 0; i < 16; ++i) {
        float xi = (i == c) ? 1.f : 0.f;
        for (int j = 0; j < i; ++j) xi -= sA[I*16 + i][I*16 + j] * x[j];
        x[i] = xi;
      }
      const float bc = sBeta[I*16 + c];
      #pragma unroll
      for (int i = 0; i < 16; ++i) {
        sVinv[I][i][c] = x[i];
        sTb[I*16 + i][I*16 + c] = f2bf(x[i] * bc);
      }
    }
    __syncthreads();  // b4

    if (wave >= 4) {
      py_step(1);
    } else {
      // S2a: M10 = V1*A10, M32 = V3*A32   (t < 256)
      const int r = t >> 4, c = t & 15;
      float m1 = 0.f, m3 = 0.f;
      #pragma unroll
      for (int kk = 0; kk < 16; ++kk) {
        m1 += sVinv[1][r][kk] * sA[16 + kk][c];
        m3 += sVinv[3][r][kk] * sA[48 + kk][32 + c];
      }
      sTmp[r][c] = m1;
      sTmp[16 + r][c] = m3;
    }
    __syncthreads();  // b5

    if (wave >= 4) {
      py_step(2);
    } else {
      // S2b: X10 = -M10*V0 ; X32 = -M32*V2  (fp32 into sA, bf16*beta into sTb)
      const int r = t >> 4, c = t & 15;
      float x1 = 0.f, x3 = 0.f;
      #pragma unroll
      for (int kk = 0; kk < 16; ++kk) {
        x1 += sTmp[r][kk] * sVinv[0][kk][c];
        x3 += sTmp[16 + r][kk] * sVinv[2][kk][c];
      }
      x1 = -x1; x3 = -x3;
      sA[16 + r][c] = x1;
      sTb[16 + r][c] = f2bf(x1 * sBeta[c]);
      sA[48 + r][32 + c] = x3;
      sTb[48 + r][32 + c] = f2bf(x3 * sBeta[32 + c]);
    }
    __syncthreads();  // b6

    if (wave >= 4) {
      py_step(3);
    } else {
      // S3a: M = A_bl * W1inv  (32x32), W1inv = [[V0,0],[X10,V1]]
      #pragma unroll
      for (int p = 0; p < 4; ++p) {
        const int idx = t + 256*p;
        const int r = idx >> 5, c = idx & 31;
        float m = 0.f;
        if (c < 16) {
          #pragma unroll
          for (int kk = 0; kk < 16; ++kk) m += sA[32 + r][kk] * sVinv[0][kk][c];
          #pragma unroll
          for (int kk = 16; kk < 32; ++kk) m += sA[32 + r][kk] * sA[kk][c];
        } else {
          #pragma unroll
          for (int kk = 16; kk < 32; ++kk) m += sA[32 + r][kk] * sVinv[1][kk - 16][c - 16];
        }
        sTmp[r][c] = m;
      }
    }
    __syncthreads();  // b7

    if (wave >= 4) {
      // PY epilogue: Y = gexp*V - kp.S  -> Y^T bf16
      #pragma unroll
      for (int vt = 0; vt < 2; ++vt) {
        short4v yw;
        #pragma unroll
        for (int reg = 0; reg < 4; ++reg) {
          const float gei = sGexp[iy0 + quad*4 + reg];
          yw[reg] = f2bf(gei * vv[vt][reg] - yacc[vt][reg]);
        }
        *(short4v*)&sYT[vt*16 + n16][iy0 + quad*4] = yw;
      }
    } else {
      // S3b: X_bl = -W2inv * M, W2inv = [[V2,0],[X32,V3]]
      #pragma unroll
      for (int p = 0; p < 4; ++p) {
        const int idx = t + 256*p;
        const int r = idx >> 5, c = idx & 31;
        float xv = 0.f;
        if (r < 16) {
          #pragma unroll
          for (int kk = 0; kk < 16; ++kk) xv += sVinv[2][r][kk] * sTmp[kk][c];
        } else {
          #pragma unroll
          for (int kk = 0; kk < 16; ++kk) xv += sA[32 + r][32 + kk] * sTmp[kk][c];
          #pragma unroll
          for (int kk = 16; kk < 32; ++kk) xv += sVinv[3][r - 16][kk - 16] * sTmp[kk][c];
        }
        sTb[32 + r][c] = f2bf(-xv * sBeta[c]);
      }
    }
    __syncthreads();  // b8

    // ---- PC: cor = T.Y -> cor^T bf16 (all 8 waves, one tile each) ----
    {
      const int ic0 = (wave >> 1) * 16, vc0 = (wave & 1) * 16;
      f32x4 cacc; cacc = 0;
      #pragma unroll
      for (int ks = 0; ks < 2; ++ks) {
        short8 af = *(const short8*)&sTb[ic0 + n16][ks*32 + quad*8];
        short8 bf = *(const short8*)&sYT[vc0 + n16][ks*32 + quad*8];
        cacc = MFMA16(af, bf, cacc);
      }
      short4v cw;
      #pragma unroll
      for (int reg = 0; reg < 4; ++reg) cw[reg] = f2bf(cacc[reg]);
      *(short4v*)&sCT[vc0 + n16][ic0 + quad*4] = cw;
    }
    __syncthreads();  // b9

    // ---- PO (waves 4-7): O = qp.S + Aqk.cor -> global
    // ---- PSU (waves 0-3): S = decay*S + kp^T.cor (in accumulators) ----
    if (wave >= 4) {
      const int io = (wave & 3) * 16;
      #pragma unroll
      for (int ks = 0; ks < 2; ++ks) {
        short8 af = *(const short8*)&sAqk[io + n16][ks*32 + quad*8];
        #pragma unroll
        for (int vt = 0; vt < 2; ++vt) {
          short8 bf = *(const short8*)&sCT[vt*16 + n16][ks*32 + quad*8];
          oacc[vt] = MFMA16(af, bf, oacc[vt]);
        }
      }
      #pragma unroll
      for (int vt = 0; vt < 2; ++vt)
        #pragma unroll
        for (int reg = 0; reg < 4; ++reg)
          op_g[(size_t)(n*kL + io + quad*4 + reg) * kDv + vt*16 + n16] = oacc[vt][reg];
    } else {
      const float decay = sGexp[kL - 1];
      Sacc[0] *= decay; Sacc[1] *= decay; Sacc[2] *= decay; Sacc[3] *= decay;
      #pragma unroll
      for (int a = 0; a < 2; ++a) {
        const int d0 = (wave & 3) * 32 + a * 16;
        #pragma unroll
        for (int ks = 0; ks < 2; ++ks) {
          short8 af;
          #pragma unroll
          for (int j = 0; j < 8; ++j) af[j] = sKp[ks*32 + quad*8 + j][d0 + n16];
          #pragma unroll
          for (int b = 0; b < 2; ++b) {
            short8 bf = *(const short8*)&sCT[b*16 + n16][ks*32 + quad*8];
            Sacc[a*2 + b] = MFMA16(af, bf, Sacc[a*2 + b]);
          }
        }
        #pragma unroll
        for (int b = 0; b < 2; ++b) {
          short4v sw;
          #pragma unroll
          for (int reg = 0; reg < 4; ++reg) sw[reg] = f2bf(Sacc[a*2 + b][reg]);
          *(short4v*)&sSb[b*16 + n16][d0 + quad*4] = sw;
        }
      }
    }
  }

  // ---- final state (fp32 from accumulators) -> d_out tail ----
  if (wave < 4) {
    #pragma unroll
    for (int a = 0; a < 2; ++a)
      #pragma unroll
      for (int b = 0; b < 2; ++b)
        #pragma unroll
        for (int reg = 0; reg < 4; ++reg) {
          const int d = (wave & 3) * 32 + a * 16 + quad * 4 + reg;
          sp_g[(size_t)d * kDv + b * 16 + n16] = Sacc[a*2 + b][reg];
        }
  }
}

}  // namespace

extern "C" void kernel_launch(void* const* d_in, const int* in_sizes, int n_in,
                              void* d_out, int out_size, void* d_ws, size_t ws_size,
                              hipStream_t stream) {
  (void)in_sizes; (void)n_in; (void)d_ws; (void)ws_size; (void)out_size;
  const float* q    = (const float*)d_in[0];
  const float* k    = (const float*)d_in[1];
  const float* v    = (const float*)d_in[2];
  const float* g    = (const float*)d_in[3];
  const float* beta = (const float*)d_in[4];
  float* out = (float*)d_out;
  gdn_mfma_kernel<<<dim3(kBH * (kDv / 32)), dim3(kThreads), 0, stream>>>(
      q, k, v, g, beta, out);
}